// Round 5
// 873.896 us; speedup vs baseline: 1.0276x; 1.0276x over previous
//
#include <hip/hip_runtime.h>

// Depthwise 3x3 conv, channel-multiplier 2, shared single-channel kernel.
// x: [B=16, H=224, W=224, C=96] f32 NHWC
// k: [3,3,1,2] f32   bias: [192] f32
// out[b,y,x, 2c+m] = sum_{dy,dx} x[b, y+dy-1, x+dx-1, c] * k[dy,dx,0,m] + bias[2c+m]
//
// R1: y-tiled threads (YT=8 output rows per thread). The 3-row stencil window is
// kept in registers, so each input row is fetched ~once (plus 2 halo rows per
// 8-row tile -> 1.25x) instead of 3x across different-XCD blocks. Non-temporal
// stores keep the 617 MB output stream from evicting halo rows out of L2.
// R3 fix: __builtin_nontemporal_store needs a native clang vector type, not
// HIP_vector_type float4 -> store through ext_vector_type(4) alias.

#define BATCH 16
#define H 224
#define W 224
#define C 96
#define CG (C / 4)        // 24 float4 channel-groups
#define CO (C * 2)        // 192 output channels
#define XT 8              // x positions per block
#define YT 8              // y rows per thread

typedef float fvec4 __attribute__((ext_vector_type(4)));

__device__ __forceinline__ float4 ld4(const float* p) { return *(const float4*)p; }

__device__ __forceinline__ void st4_nt(float* p, float4 v) {
    fvec4 t; t.x = v.x; t.y = v.y; t.z = v.z; t.w = v.w;
    __builtin_nontemporal_store(t, (fvec4*)p);
}

template <bool XEDGE>
__device__ __forceinline__ void conv_tile(
    const float* __restrict__ xb,   // x + b*H*W*C + cg*4
    const float* __restrict__ k,
    const float* __restrict__ bias,
    float* __restrict__ out,
    int b, int y0, int xo, int cg)
{
    // 18 weights; uniform address -> scalar loads into SGPRs
    float w[3][3][2];
#pragma unroll
    for (int dy = 0; dy < 3; ++dy)
#pragma unroll
        for (int dx = 0; dx < 3; ++dx)
#pragma unroll
            for (int m = 0; m < 2; ++m)
                w[dy][dx][m] = k[(dy * 3 + dx) * 2 + m];

    // accA[r] = out channels 8cg+0..3, accB[r] = 8cg+4..7, for output row y0+r
    float4 accA[YT], accB[YT];
#pragma unroll
    for (int r = 0; r < YT; ++r) {
        accA[r] = make_float4(0.f, 0.f, 0.f, 0.f);
        accB[r] = make_float4(0.f, 0.f, 0.f, 0.f);
    }

    // Sweep YT+2 input rows; input row yy feeds output rows yy-1, yy, yy+1
    // (weight index dy = iy - r after unroll -> all indices compile-time).
#pragma unroll
    for (int iy = 0; iy < YT + 2; ++iy) {
        const int yy = y0 + iy - 1;
        if ((unsigned)yy >= (unsigned)H) continue;   // SAME zero-pad rows
        const float* row = xb + ((size_t)yy * W + (xo - 1)) * C;
        float4 va, vb, vc;
        if (XEDGE) {
            va = (xo >= 1)     ? ld4(row)         : make_float4(0.f, 0.f, 0.f, 0.f);
            vb =                 ld4(row + C);
            vc = (xo <= W - 2) ? ld4(row + 2 * C) : make_float4(0.f, 0.f, 0.f, 0.f);
        } else {
            va = ld4(row);
            vb = ld4(row + C);
            vc = ld4(row + 2 * C);
        }
#pragma unroll
        for (int dy = 0; dy < 3; ++dy) {
            const int r = iy - dy;          // local output row
            if (r < 0 || r >= YT) continue; // resolved at compile time
            const float q00 = w[dy][0][0], q01 = w[dy][0][1];
            const float q10 = w[dy][1][0], q11 = w[dy][1][1];
            const float q20 = w[dy][2][0], q21 = w[dy][2][1];
            accA[r].x += va.x * q00; accA[r].y += va.x * q01;
            accA[r].z += va.y * q00; accA[r].w += va.y * q01;
            accB[r].x += va.z * q00; accB[r].y += va.z * q01;
            accB[r].z += va.w * q00; accB[r].w += va.w * q01;
            accA[r].x += vb.x * q10; accA[r].y += vb.x * q11;
            accA[r].z += vb.y * q10; accA[r].w += vb.y * q11;
            accB[r].x += vb.z * q10; accB[r].y += vb.z * q11;
            accB[r].z += vb.w * q10; accB[r].w += vb.w * q11;
            accA[r].x += vc.x * q20; accA[r].y += vc.x * q21;
            accA[r].z += vc.y * q20; accA[r].w += vc.y * q21;
            accB[r].x += vc.z * q20; accB[r].y += vc.z * q21;
            accB[r].z += vc.w * q20; accB[r].w += vc.w * q21;
        }
    }

    const float4 bA = ((const float4*)bias)[2 * cg + 0];
    const float4 bB = ((const float4*)bias)[2 * cg + 1];
#pragma unroll
    for (int r = 0; r < YT; ++r) {
        float4 oa = accA[r], ob = accB[r];
        oa.x += bA.x; oa.y += bA.y; oa.z += bA.z; oa.w += bA.w;
        ob.x += bB.x; ob.y += bB.y; ob.z += bB.z; ob.w += bB.w;
        float* o = out + (((size_t)b * H + (y0 + r)) * W + xo) * CO + (size_t)cg * 8;
        st4_nt(o + 0, oa);
        st4_nt(o + 4, ob);
    }
}

__global__ __launch_bounds__(CG * XT) void dwconv_kernel(
    const float* __restrict__ x,
    const float* __restrict__ k,
    const float* __restrict__ bias,
    float* __restrict__ out)
{
    const int cg = threadIdx.x;                    // 0..23 channel group
    const int xo = blockIdx.x * XT + threadIdx.y;  // 0..223
    const int y0 = blockIdx.y * YT;                // 0,8,...,216
    const int b  = blockIdx.z;

    const float* xb = x + (size_t)b * H * W * C + (size_t)cg * 4;

    if (blockIdx.x == 0 || blockIdx.x == gridDim.x - 1)
        conv_tile<true>(xb, k, bias, out, b, y0, xo, cg);
    else
        conv_tile<false>(xb, k, bias, out, b, y0, xo, cg);
}

extern "C" void kernel_launch(void* const* d_in, const int* in_sizes, int n_in,
                              void* d_out, int out_size, void* d_ws, size_t ws_size,
                              hipStream_t stream) {
    const float* x    = (const float*)d_in[0];
    const float* k    = (const float*)d_in[1];
    const float* bias = (const float*)d_in[2];
    float* out = (float*)d_out;

    dim3 block(CG, XT, 1);                 // 192 threads = 3 waves
    dim3 grid(W / XT, H / YT, BATCH);      // 28 x 28 x 16
    hipLaunchKernelGGL(dwconv_kernel, grid, block, 0, stream, x, k, bias, out);
}